// Round 4
// baseline (1309.681 us; speedup 1.0000x reference)
//
#include <hip/hip_runtime.h>
#include <hip/hip_bf16.h>
#include <cstdint>
#include <cstddef>

#define D_MODEL 512
#define HIDDEN  2048
#define N_EXP   8
#define NTOK    8192          // 4 * 2048 tokens
#define MAXROWS (NTOK * 2)
#define MAXT2   1056          // 4 * (sum_e ceil(n_e/64)) <= 4*264

typedef unsigned short u16;
typedef _Float16 half8 __attribute__((ext_vector_type(8)));
typedef float   f32x16 __attribute__((ext_vector_type(16)));

#define SBAR()  __builtin_amdgcn_s_barrier()
#define LGKM0() asm volatile("s_waitcnt lgkmcnt(0)" ::: "memory")

// ---------------------------------------------------------------------------
// helpers: fp16 hi/lo split packing
// ---------------------------------------------------------------------------
__device__ __forceinline__ unsigned pk2(_Float16 a, _Float16 b) {
    unsigned short ua, ub;
    __builtin_memcpy(&ua, &a, 2); __builtin_memcpy(&ub, &b, 2);
    return (unsigned)ua | ((unsigned)ub << 16);
}
__device__ __forceinline__ void split2(float a, float b, unsigned& h, unsigned& l) {
    _Float16 ha = (_Float16)a, hb = (_Float16)b;      // RNE
    float ra = a - (float)ha, rb = b - (float)hb;     // exact residuals
    h = pk2(ha, hb);
    l = pk2((_Float16)ra, (_Float16)rb);
}
__device__ __forceinline__ half8 h8(uint2 lo, uint2 hi) {
    union { unsigned u[4]; half8 h; } t;
    t.u[0] = lo.x; t.u[1] = lo.y; t.u[2] = hi.x; t.u[3] = hi.y;
    return t.h;
}
__device__ __forceinline__ half8 h8c(uint4 v) {
    union { uint4 u; half8 h; } t; t.u = v; return t.h;
}
__device__ __forceinline__ f32x16 mfma16(half8 a, half8 b, f32x16 c) {
    return __builtin_amdgcn_mfma_f32_32x32x16_f16(a, b, c, 0, 0, 0);
}

// ---------------------------------------------------------------------------
// Gate: one 64-lane wave per token. scores = x . Wg + bg ; top-2 ; softmax.
// ---------------------------------------------------------------------------
__global__ __launch_bounds__(256) void gate_kernel(
    const float* __restrict__ x, const float* __restrict__ Wg,
    const float* __restrict__ bg,
    int* __restrict__ eidx, float* __restrict__ ewt, int* __restrict__ cnt)
{
    const int wid  = threadIdx.x >> 6;
    const int lane = threadIdx.x & 63;
    const int t = blockIdx.x * 4 + wid;
    const float* xr = x + (size_t)t * D_MODEL;

    float p[8] = {0.f,0.f,0.f,0.f,0.f,0.f,0.f,0.f};
    for (int i = lane; i < D_MODEL; i += 64) {
        const float xv = xr[i];
        const float4 a = *(const float4*)(Wg + (size_t)i * 8);
        const float4 b = *(const float4*)(Wg + (size_t)i * 8 + 4);
        p[0] += xv*a.x; p[1] += xv*a.y; p[2] += xv*a.z; p[3] += xv*a.w;
        p[4] += xv*b.x; p[5] += xv*b.y; p[6] += xv*b.z; p[7] += xv*b.w;
    }
    #pragma unroll
    for (int off = 32; off >= 1; off >>= 1) {
        #pragma unroll
        for (int e = 0; e < 8; ++e) p[e] += __shfl_xor(p[e], off, 64);
    }
    if (lane == 0) {
        float s[8];
        #pragma unroll
        for (int e = 0; e < 8; ++e) s[e] = p[e] + bg[e];
        int e1 = 0; float v1 = s[0];
        #pragma unroll
        for (int e = 1; e < 8; ++e) if (s[e] > v1) { v1 = s[e]; e1 = e; }
        int e2 = -1; float v2 = -3.0e38f;
        #pragma unroll
        for (int e = 0; e < 8; ++e) if (e != e1 && s[e] > v2) { v2 = s[e]; e2 = e; }
        const float w1 = 1.f / (1.f + expf(v2 - v1));
        eidx[2*t]   = e1;  eidx[2*t+1] = e2;
        ewt [2*t]   = w1;  ewt [2*t+1] = 1.f - w1;
        atomicAdd(&cnt[e1], 1);
        atomicAdd(&cnt[e2], 1);
    }
}

// ---------------------------------------------------------------------------
// Scan + flattened (tile, hc) work table. Slot p -> expert p%8 (XCD pin via
// block->XCD round robin); ordered (hc, s, e) so all CUs of an XCD stream the
// SAME 2MB weight chunk concurrently (L2 broadcast).
// ---------------------------------------------------------------------------
__global__ __launch_bounds__(1024) void scan_kernel(
    const int* __restrict__ cnt, int* __restrict__ offs, int* __restrict__ cur,
    int* __restrict__ tileTab)
{
    __shared__ int nt[8];
    const int t = threadIdx.x;
    if (t == 0) {
        int run = 0;
        #pragma unroll
        for (int e = 0; e < 8; ++e) {
            offs[e] = run; cur[e] = run; run += cnt[e];
            nt[e] = (cnt[e] + 63) >> 6;
        }
    }
    __syncthreads();
    {
        const int e = t & 7, i = t >> 3;
        const int hcv = i >> 5, sv = i & 31;
        tileTab[t] = (sv < nt[e]) ? ((e << 24) | (sv << 8) | hcv) : -1;
    }
    if (t < MAXT2 - 1024) tileTab[1024 + t] = -1;
    __syncthreads();
    if (t == 0) {   // leftovers (experts needing > 32 tiles)
        int fp = 0;
        for (int e = 0; e < 8; ++e)
            for (int sv = 32; sv < nt[e]; ++sv)
                for (int hcv = 0; hcv < 4; ++hcv) {
                    while (tileTab[fp] >= 0) ++fp;
                    tileTab[fp] = (e << 24) | (sv << 8) | hcv;
                }
    }
}

__global__ __launch_bounds__(256) void route_kernel(
    const int* __restrict__ eidx, const float* __restrict__ ewt,
    int* __restrict__ cur, int* __restrict__ rows, float* __restrict__ rwt)
{
    const int t = blockIdx.x * 256 + threadIdx.x;
    if (t >= NTOK) return;
    #pragma unroll
    for (int k = 0; k < 2; ++k) {
        const int e = eidx[2*t + k];
        const int pos = atomicAdd(&cur[e], 1);
        rows[pos] = t;
        rwt [pos] = ewt[2*t + k];
    }
}

// ---------------------------------------------------------------------------
// conv_w1: W1^T fp16 hi/lo planes, fragment-direct layout:
//   W1c[e][hc4][q32][pl2][g2][h512][dj8]   (piece q covers d = q*16 + g*8 + dj)
// One 16B chunk per (q,pl,g,h) = one global_load_dwordx4 in the main kernel.
// ---------------------------------------------------------------------------
__global__ __launch_bounds__(256) void conv_w1(const float* __restrict__ W1,
                                               u16* __restrict__ W1c)
{
    const int e = blockIdx.z;
    const int gh0 = blockIdx.x * 64;    // over HIDDEN (2048)
    const int d0  = blockIdx.y * 64;    // over D_MODEL (512)
    __shared__ float T[64][65];         // [d][h]
    const int hl = threadIdx.x & 63, q4 = threadIdx.x >> 6;
    const float* src = W1 + (size_t)e * D_MODEL * HIDDEN;
    #pragma unroll
    for (int rr = 0; rr < 16; ++rr) {
        const int d = rr*4 + q4;
        T[d][hl] = src[(size_t)(d0 + d) * HIDDEN + gh0 + hl];
    }
    __syncthreads();
    const int hc = gh0 >> 9, hloc0 = gh0 & 511;
    const int q0 = d0 >> 4;
    #pragma unroll
    for (int g = 0; g < 2; ++g) {
        float v[8];
        #pragma unroll
        for (int j = 0; j < 8; ++j) v[j] = T[q4*16 + g*8 + j][hl];
        unsigned hh[4], ll[4];
        #pragma unroll
        for (int p = 0; p < 4; ++p) split2(v[2*p], v[2*p+1], hh[p], ll[p]);
        u16* dst = W1c + ((((size_t)(e*4 + hc)*32 + (q0 + q4))*2 + 0)*2 + g)*4096
                       + (size_t)(hloc0 + hl)*8;
        *(uint4*)dst          = make_uint4(hh[0], hh[1], hh[2], hh[3]);
        *(uint4*)(dst + 8192) = make_uint4(ll[0], ll[1], ll[2], ll[3]);   // pl=1
    }
}

// conv_w2: W2^T planes, fragment-direct layout:
//   W2c[e][hc4][r32][pl2][g2][d512][dj8]
//   element j at (g): h_loc = (g + 2*(j>>2))*4 + (j&3); h = hc*512 + r*16 + h_loc
// ---------------------------------------------------------------------------
__global__ __launch_bounds__(256) void conv_w2(const float* __restrict__ W2,
                                               u16* __restrict__ W2c)
{
    const int e = blockIdx.z;
    const int gh0 = blockIdx.x * 64;    // over HIDDEN
    const int d0  = blockIdx.y * 64;    // over D_MODEL
    __shared__ float T[64][65];         // [h][d]
    const int dl = threadIdx.x & 63, s4 = threadIdx.x >> 6;
    const float* src = W2 + (size_t)e * HIDDEN * D_MODEL;
    #pragma unroll
    for (int rr = 0; rr < 16; ++rr) {
        const int h = rr*4 + s4;
        T[h][dl] = src[(size_t)(gh0 + h) * D_MODEL + d0 + dl];
    }
    __syncthreads();
    const int hc = gh0 >> 9, r0 = (gh0 & 511) >> 4;
    #pragma unroll
    for (int g = 0; g < 2; ++g) {
        float v[8];
        #pragma unroll
        for (int j = 0; j < 8; ++j) {
            const int h_loc = (g + 2*(j >> 2))*4 + (j & 3);
            v[j] = T[s4*16 + h_loc][dl];
        }
        unsigned hh[4], ll[4];
        #pragma unroll
        for (int p = 0; p < 4; ++p) split2(v[2*p], v[2*p+1], hh[p], ll[p]);
        u16* dst = W2c + ((((size_t)(e*4 + hc)*32 + (r0 + s4))*2 + 0)*2 + g)*4096
                       + (size_t)(d0 + dl)*8;
        *(uint4*)dst          = make_uint4(hh[0], hh[1], hh[2], hh[3]);
        *(uint4*)(dst + 8192) = make_uint4(ll[0], ll[1], ll[2], ll[3]);
    }
}

// ---------------------------------------------------------------------------
// Fused MoE expert kernel v2. Block = (expert, 64-token tile, hc chunk of 512
// hidden). Weights load global->VGPR directly (no weight LDS: no cross-wave
// weight reuse exists), 1-piece-ahead register prefetch; compiler emits the
// counted vmcnt pipeline automatically. Barriers: 3 slab swaps in Phase A,
// 1 per piece in Phase B (LGKM0+SBAR only — vmcnt never drained mid-loop).
// ---------------------------------------------------------------------------
__global__ __launch_bounds__(512, 2) void moe_mfma(
    const float* __restrict__ x,
    const u16* __restrict__ W1c, const u16* __restrict__ W2c,
    const float* __restrict__ b1, const float* __restrict__ b2,
    const int* __restrict__ cnt, const int* __restrict__ offs,
    const int* __restrict__ rows, const float* __restrict__ rwt,
    const int* __restrict__ tileTab,
    float* __restrict__ out)
{
    const int tv = tileTab[blockIdx.x];
    if (tv < 0) return;
    const int e  = tv >> 24;
    const int s  = (tv >> 8) & 0xff;
    const int hc = tv & 3;
    const int n  = cnt[e];
    const int base = offs[e];
    const int t0 = s << 6;
    const int mcount = min(64, n - t0);

    const int tid  = threadIdx.x;
    const int wv   = tid >> 6;        // 0..7
    const int lane = tid & 63;
    const int g    = lane >> 5;       // 0/1 lane-group
    const int l31  = lane & 31;

    __shared__ __align__(16) u16  Xs[2][2][16][64][8];   // 64 KB X slab dbuf
    __shared__ __align__(16) u16  Hp[2][2][4][64][4];    // 8 KB H piece dbuf
    __shared__ int   toks_s[64];
    __shared__ float wts_s[64];

    if (tid < 64) {
        int tk = 0; float ww = 0.f;
        if (tid < mcount) { tk = rows[base + t0 + tid]; ww = rwt[base + t0 + tid]; }
        toks_s[tid] = tk; wts_s[tid] = ww;
    }
    __syncthreads();

    const u16* W1b = W1c + (size_t)(e*4 + hc) * 32 * 16384;
    const u16* W2b = W2c + (size_t)(e*4 + hc) * 32 * 16384;
    const int rA0 = (2*wv + 0)*32 + l31;   // this wave's rows (h in A, d in B)
    const int rA1 = (2*wv + 1)*32 + l31;

    auto ldW = [&](const u16* Wb, uint4 (&aw)[2][2], int q) {
        const u16* p = Wb + (size_t)q * 16384 + g * 4096;
        aw[0][0] = *(const uint4*)(p +        (size_t)rA0 * 8);
        aw[0][1] = *(const uint4*)(p + 8192 + (size_t)rA0 * 8);
        aw[1][0] = *(const uint4*)(p +        (size_t)rA1 * 8);
        aw[1][1] = *(const uint4*)(p + 8192 + (size_t)rA1 * 8);
    };

    float4 xr0, xr1, xr2, xr3;        // T14-split X staging registers
    auto stageX_load = [&](int ds) {
        const float* xp = x + (size_t)toks_s[lane] * D_MODEL + ds*128 + wv*16;
        xr0 = *(const float4*)(xp + 0);  xr1 = *(const float4*)(xp + 4);
        xr2 = *(const float4*)(xp + 8);  xr3 = *(const float4*)(xp + 12);
    };
    auto stageX_write = [&](int ds) {
        const int sb = ds & 1;
        unsigned h[4], l[4];
        split2(xr0.x, xr0.y, h[0], l[0]); split2(xr0.z, xr0.w, h[1], l[1]);
        split2(xr1.x, xr1.y, h[2], l[2]); split2(xr1.z, xr1.w, h[3], l[3]);
        *(uint4*)&Xs[sb][0][wv*2][lane][0]   = make_uint4(h[0], h[1], h[2], h[3]);
        *(uint4*)&Xs[sb][1][wv*2][lane][0]   = make_uint4(l[0], l[1], l[2], l[3]);
        split2(xr2.x, xr2.y, h[0], l[0]); split2(xr2.z, xr2.w, h[1], l[1]);
        split2(xr3.x, xr3.y, h[2], l[2]); split2(xr3.z, xr3.w, h[3], l[3]);
        *(uint4*)&Xs[sb][0][wv*2+1][lane][0] = make_uint4(h[0], h[1], h[2], h[3]);
        *(uint4*)&Xs[sb][1][wv*2+1][lane][0] = make_uint4(l[0], l[1], l[2], l[3]);
    };

    f32x16 d1[2][2], d2[2][2];
    #pragma unroll
    for (int a = 0; a < 2; ++a)
        #pragma unroll
        for (int b = 0; b < 2; ++b)
            #pragma unroll
            for (int r = 0; r < 16; ++r) { d1[a][b][r] = 0.f; d2[a][b][r] = 0.f; }

    unsigned hpk[2][2][2][2][4];   // [mfs][c][tf][pl][q] — literal-indexed only

    auto writeH = [&](u16* hp, const unsigned (&hk)[2][2][4]) {
        #pragma unroll
        for (int tf = 0; tf < 2; ++tf)
            #pragma unroll
            for (int pl = 0; pl < 2; ++pl) {
                *(uint2*)&hp[((pl*4 + g    )*64 + tf*32 + l31)*4] = make_uint2(hk[tf][pl][0], hk[tf][pl][1]);
                *(uint2*)&hp[((pl*4 + g + 2)*64 + tf*32 + l31)*4] = make_uint2(hk[tf][pl][2], hk[tf][pl][3]);
            }
    };
    auto ownerH = [&](int pn) {            // write H piece pn into Hp[pn&1]
        if (wv != (pn >> 2)) return;       // piece owner wave
        u16* hp = &Hp[pn & 1][0][0][0][0];
        const int mfs = (pn >> 1) & 1;
        if (mfs) { if (pn & 1) writeH(hp, hpk[1][1]); else writeH(hp, hpk[1][0]); }
        else     { if (pn & 1) writeH(hp, hpk[0][1]); else writeH(hp, hpk[0][0]); }
    };

    auto computeA = [&](const uint4 (&A)[2][2], int sb, int pa) {
        half8 bx[2][2];
        #pragma unroll
        for (int tf = 0; tf < 2; ++tf)
            #pragma unroll
            for (int pl = 0; pl < 2; ++pl)
                bx[tf][pl] = *(const half8*)&Xs[sb][pl][2*pa + g][tf*32 + l31][0];
        __builtin_amdgcn_s_setprio(1);
        #pragma unroll
        for (int mfs = 0; mfs < 2; ++mfs) {
            const half8 a0 = h8c(A[mfs][0]), a1 = h8c(A[mfs][1]);
            #pragma unroll
            for (int tf = 0; tf < 2; ++tf) {
                d1[mfs][tf] = mfma16(a0, bx[tf][0], d1[mfs][tf]);
                d1[mfs][tf] = mfma16(a0, bx[tf][1], d1[mfs][tf]);
                d1[mfs][tf] = mfma16(a1, bx[tf][0], d1[mfs][tf]);
            }
        }
        __builtin_amdgcn_s_setprio(0);
    };
    auto computeB = [&](const uint4 (&A)[2][2], int rb) {
        const u16* hp = &Hp[rb][0][0][0][0];
        half8 bh[2][2];
        #pragma unroll
        for (int tf = 0; tf < 2; ++tf)
            #pragma unroll
            for (int pl = 0; pl < 2; ++pl) {
                uint2 lo = *(const uint2*)&hp[((pl*4 + g    )*64 + tf*32 + l31)*4];
                uint2 hi = *(const uint2*)&hp[((pl*4 + g + 2)*64 + tf*32 + l31)*4];
                bh[tf][pl] = h8(lo, hi);
            }
        __builtin_amdgcn_s_setprio(1);
        #pragma unroll
        for (int mfs = 0; mfs < 2; ++mfs) {
            const half8 a0 = h8c(A[mfs][0]), a1 = h8c(A[mfs][1]);
            #pragma unroll
            for (int tf = 0; tf < 2; ++tf) {
                d2[mfs][tf] = mfma16(a0, bh[tf][0], d2[mfs][tf]);
                d2[mfs][tf] = mfma16(a0, bh[tf][1], d2[mfs][tf]);
                d2[mfs][tf] = mfma16(a1, bh[tf][0], d2[mfs][tf]);
            }
        }
        __builtin_amdgcn_s_setprio(0);
    };
    auto finishH = [&]() {
        const float* b1p = b1 + (size_t)e * HIDDEN + hc * 512;
        #pragma unroll
        for (int mfs = 0; mfs < 2; ++mfs) {
            const int hbase = (2*wv + mfs) * 32;
            float bias[16];
            #pragma unroll
            for (int r = 0; r < 16; ++r)
                bias[r] = b1p[hbase + (r & 3) + 8*(r >> 2) + 4*g];
            #pragma unroll
            for (int tf = 0; tf < 2; ++tf) {
                const float wt = wts_s[tf*32 + l31];
                float t[16];
                #pragma unroll
                for (int r = 0; r < 16; ++r)
                    t[r] = fmaxf(d1[mfs][tf][r] + bias[r], 0.f) * wt;
                #pragma unroll
                for (int c = 0; c < 2; ++c)
                    #pragma unroll
                    for (int q = 0; q < 4; ++q)
                        split2(t[8*c + 2*q], t[8*c + 2*q + 1],
                               hpk[mfs][c][tf][0][q], hpk[mfs][c][tf][1][q]);
            }
        }
    };

    // prologue: issue first weight piece, stage X slab 0
    uint4 awp[2][2][2];
    ldW(W1b, awp[0], 0);
    stageX_load(0);
    stageX_write(0);
    __syncthreads();

    // ---- Phase A: D1 = W1^T X^T, 32 k-pieces over d ----
    #pragma unroll 2
    for (int q = 0; q < 32; ++q) {
        const int pa = q & 7, ds = q >> 3;
        if (q < 31) ldW(W1b, awp[(q + 1) & 1], q + 1);
        else        ldW(W2b, awp[(q + 1) & 1], 0);      // prefetch Phase B piece 0
        computeA(awp[q & 1], ds & 1, pa);
        if (pa == 4 && ds < 3) stageX_load(ds + 1);
        if (pa == 5 && ds < 3) stageX_write(ds + 1);
        if (pa == 7 && ds < 3) { LGKM0(); SBAR(); }
    }

    finishH();     // d1 -> hpk (bias+relu+gate-scale, fp16 split)
    ownerH(0);
    LGKM0(); SBAR();

    // ---- Phase B: D2 += W2^T H, 32 k-pieces over h ----
    #pragma unroll 2
    for (int r = 0; r < 32; ++r) {
        if (r < 31) { ldW(W2b, awp[(r + 1) & 1], r + 1); ownerH(r + 1); }
        computeB(awp[r & 1], r & 1);
        LGKM0(); SBAR();
    }

    // ---- epilogue: transpose D2[d][tok] via LDS, coalesced atomicAdd ----
    float* Ot = (float*)&Xs[0][0][0][0][0];   // [64][129] f32 (33KB), Xs is dead
    const float* b2e = b2 + (size_t)e * D_MODEL;
    #pragma unroll 1
    for (int c = 0; c < 4; ++c) {
        if ((wv >> 1) == c) {
            #pragma unroll
            for (int mfs = 0; mfs < 2; ++mfs)
                #pragma unroll
                for (int tf = 0; tf < 2; ++tf)
                    #pragma unroll
                    for (int r = 0; r < 16; ++r) {
                        const int dl = (wv & 1)*64 + mfs*32 + (r & 3) + 8*(r >> 2) + 4*g;
                        Ot[(tf*32 + l31)*129 + dl] = d2[mfs][tf][r];
                    }
        }
        __syncthreads();
        #pragma unroll
        for (int it = 0; it < 16; ++it) {
            const int flat = it*512 + tid;
            const int tk = flat >> 7, dl = flat & 127;
            if (tk < mcount) {
                float v = Ot[tk*129 + dl];
                if (hc == 0) v += wts_s[tk] * b2e[c*128 + dl];   // b2 exactly once
                atomicAdd(out + (size_t)toks_s[tk]*D_MODEL + c*128 + dl, v);
            }
        }
        __syncthreads();
    }
}

// ---------------------------------------------------------------------------
// Fallback fp32 expert kernel (only if ws too small for converted weights).
// ---------------------------------------------------------------------------
__global__ __launch_bounds__(512) void moe_fp32(
    const float* __restrict__ x,
    const float* __restrict__ W1, const float* __restrict__ b1,
    const float* __restrict__ W2, const float* __restrict__ b2,
    const int* __restrict__ cnt, const int* __restrict__ offs,
    const int* __restrict__ rows, const float* __restrict__ rwt,
    float* __restrict__ out)
{
    const int e  = blockIdx.y;
    const int n  = cnt[e];
    const int t0 = blockIdx.x * 32;
    if (t0 >= n) return;
    const int base   = offs[e];
    const int mcount = min(32, n - t0);

    __shared__ float Xs[32 * 512];
    __shared__ float Ws[32 * 512];
    __shared__ float Hs[32 * 36];
    __shared__ int   toks[32];
    __shared__ float wts[32];

    const int tid  = threadIdx.x;
    const int w    = tid >> 6;
    const int lane = tid & 63;

    if (tid < 32) {
        int tk = 0; float ww = 0.f;
        if (tid < mcount) { tk = rows[base + t0 + tid]; ww = rwt[base + t0 + tid]; }
        toks[tid] = tk; wts[tid] = ww;
    }
    __syncthreads();

    float4* Xs4 = (float4*)Xs;
    for (int i = tid; i < 32 * 128; i += 512) {
        const int m = i >> 7, c4 = i & 127;
        float4 v = make_float4(0.f, 0.f, 0.f, 0.f);
        if (m < mcount) v = *(const float4*)(x + (size_t)toks[m] * D_MODEL + c4 * 4);
        Xs4[m * 128 + (c4 ^ (m & 7))] = v;
    }

    const int mA = (lane & 15) | ((w & 1) << 4);
    const int hA = ((w >> 1) << 3) | ((lane >> 4) << 1);
    const int sx = mA & 7;
    const int s0 = (hA >> 2) & 7;
    const int mB = (w & 1) << 4;
    const int dB = ((w >> 1) << 7) + lane * 2;

    float2 acc[16];
    #pragma unroll
    for (int mi = 0; mi < 16; ++mi) acc[mi] = make_float2(0.f, 0.f);

    const float* W1e = W1 + (size_t)e * (D_MODEL * HIDDEN);
    const float* W2e = W2 + (size_t)e * (HIDDEN * D_MODEL);
    const float* b1e = b1 + (size_t)e * HIDDEN;

    const int hq     = tid & 7;
    const int dstage = tid >> 3;
    float4* Ws4 = (float4*)Ws;

    for (int hcc = 0; hcc < HIDDEN / 32; ++hcc) {
        const int h0 = hcc * 32;
        {
            const float* src = W1e + h0 + hq * 4;
            #pragma unroll
            for (int pp = 0; pp < 8; ++pp) {
                const int d = pp * 64 + dstage;
                const float4 v = *(const float4*)(src + (size_t)d * HIDDEN);
                const int dsz = d ^ (hq << 2);
                Ws[(hq * 4 + 0) * 512 + dsz] = v.x;
                Ws[(hq * 4 + 1) * 512 + dsz] = v.y;
                Ws[(hq * 4 + 2) * 512 + dsz] = v.z;
                Ws[(hq * 4 + 3) * 512 + dsz] = v.w;
            }
        }
        __syncthreads();
        {
            const float4* Xr  = Xs4 + mA * 128;
            const float4* Wr0 = Ws4 + hA * 128;
            const float4* Wr1 = Ws4 + (hA + 1) * 128;
            float4 A0 = make_float4(0,0,0,0), A1 = make_float4(0,0,0,0);
            #pragma unroll 4
            for (int d4 = 0; d4 < 128; ++d4) {
                const float4 xv = Xr[d4 ^ sx];
                const float4 u  = Wr0[d4 ^ s0];
                const float4 vv = Wr1[d4 ^ s0];
                A0.x += xv.x*u.x;  A0.y += xv.y*u.y;  A0.z += xv.z*u.z;  A0.w += xv.w*u.w;
                A1.x += xv.x*vv.x; A1.y += xv.y*vv.y; A1.z += xv.z*vv.z; A1.w += xv.w*vv.w;
            }
            const float a0 = (A0.x + A0.y) + (A0.z + A0.w);
            const float a1 = (A1.x + A1.y) + (A1.z + A1.w);
            const float ww = wts[mA];
            Hs[mA * 36 + hA]     = fmaxf(a0 + b1e[h0 + hA],     0.f) * ww;
            Hs[mA * 36 + hA + 1] = fmaxf(a1 + b1e[h0 + hA + 1], 0.f) * ww;
        }
        __syncthreads();
        {
            const float* w2ptr = W2e + (size_t)h0 * D_MODEL + dB;
            #pragma unroll
            for (int qq = 0; qq < 8; ++qq) {
                const float2 wv0 = *(const float2*)(w2ptr + (size_t)(qq*4 + 0) * D_MODEL);
                const float2 wv1 = *(const float2*)(w2ptr + (size_t)(qq*4 + 1) * D_MODEL);
                const float2 wv2 = *(const float2*)(w2ptr + (size_t)(qq*4 + 2) * D_MODEL);
                const float2 wv3 = *(const float2*)(w2ptr + (size_t)(qq*4 + 3) * D_MODEL);
                #pragma unroll
                for (int mi = 0; mi < 16; ++mi) {
                    const float4 hv = *(const float4*)&Hs[(mB + mi) * 36 + qq * 4];
                    acc[mi].x += hv.x*wv0.x + hv.y*wv1.x + hv.z*wv2.x + hv.w*wv3.x;
                    acc[mi].y += hv.x*wv0.y + hv.y*wv1.y + hv.z*wv2.y + hv.w*wv3.y;
                }
            }
        }
    }

    const float2 b2v = *(const float2*)(b2 + (size_t)e * D_MODEL + dB);
    #pragma unroll
    for (int mi = 0; mi < 16; ++mi) {
        const int m = mB + mi;
        if (m < mcount) {
            const float ww = wts[m];
            float* op = out + (size_t)toks[m] * D_MODEL + dB;
            atomicAdd(op,     acc[mi].x + ww * b2v.x);
            atomicAdd(op + 1, acc[mi].y + ww * b2v.y);
        }
    }
}

// ---------------------------------------------------------------------------
extern "C" void kernel_launch(void* const* d_in, const int* in_sizes, int n_in,
                              void* d_out, int out_size, void* d_ws, size_t ws_size,
                              hipStream_t stream)
{
    const float* x  = (const float*)d_in[0];
    const float* W1 = (const float*)d_in[1];
    const float* b1 = (const float*)d_in[2];
    const float* W2 = (const float*)d_in[3];
    const float* b2 = (const float*)d_in[4];
    const float* Wg = (const float*)d_in[5];
    const float* bg = (const float*)d_in[6];
    float* out = (float*)d_out;

    const size_t WC_BYTES = (size_t)1024 * 32768;           // 32 MB each
    const size_t NEED = 2 * WC_BYTES + (1u << 20);
    const bool fast = (ws_size >= NEED);

    char* wsc = (char*)d_ws;
    u16* W1c = (u16*)wsc;
    u16* W2c = (u16*)(wsc + WC_BYTES);
    char* rbase = fast ? (wsc + 2 * WC_BYTES) : wsc;

    int*   cnt  = (int*)rbase;
    int*   offs = cnt + 8;
    int*   curp = offs + 8;
    int*   eidx = curp + 8;
    float* ewt  = (float*)(eidx + 2 * NTOK);
    int*   rows = (int*)(ewt + 2 * NTOK);
    float* rwt  = (float*)(rows + MAXROWS);
    int*   tileTab = (int*)(rwt + MAXROWS);

    hipMemsetAsync(cnt, 0, 24 * sizeof(int), stream);
    hipMemsetAsync(d_out, 0, (size_t)out_size * sizeof(float), stream);

    gate_kernel <<<NTOK / 4,   256,  0, stream>>>(x, Wg, bg, eidx, ewt, cnt);
    scan_kernel <<<1,          1024, 0, stream>>>(cnt, offs, curp, tileTab);
    route_kernel<<<NTOK / 256, 256,  0, stream>>>(eidx, ewt, curp, rows, rwt);

    if (fast) {
        conv_w1<<<dim3(32, 8, 8), 256, 0, stream>>>(W1, W1c);
        conv_w2<<<dim3(32, 8, 8), 256, 0, stream>>>(W2, W2c);
        moe_mfma<<<MAXT2, 512, 0, stream>>>(x, W1c, W2c, b1, b2,
                                            cnt, offs, rows, rwt, tileTab, out);
    } else {
        moe_fp32<<<dim3(512, 8), 512, 0, stream>>>(x, W1, b1, W2, b2,
                                                   cnt, offs, rows, rwt, out);
    }
}